// Round 8
// baseline (189.240 us; speedup 1.0000x reference)
//
#include <hip/hip_runtime.h>

// VQGAN VectorQuantizer forward — MFMA + counted-vmcnt pipeline edition.
// z: (32,256,32,32) f32, emb: (1024,256) f32.
// d_out (float): [0..8388607] z_q | [8388608] loss | [8388609..] indices.
//
// Numerics: replicate np-f32 quantized score s = fl(fl(A+B) - 2*dot).
// dot via 3 bf16 MFMA GEMMs (z1e1+z1e2+z2e1; exact 2-term RNE splits),
// fragment/accumulation order identical to rounds 6/7 (both passed). Rows with
// top-2 margin < 1.5e-4 re-solved exactly by k_refine (round-3 serial-fmaf
// chain, candidate chunks only). Loss = 1.25 * mean best score.
//
// z_q region of d_out (dead until k_gather) holds z1t,z2t bf16 tiles (32 MB).
// Other scratch in d_ws (~7.3 MB):
#define WS_B 0            // [1024]   B_k = ||emb_k||^2
#define WS_A 1024         // [32768]  A_n = ||z_n||^2
#define WS_PV1 33792      // [16][32768] per-chunk best score
#define WS_PI1 558080     // [16][32768] per-chunk best index
#define WS_PV2 1082368    // [16][32768] per-chunk 2nd-best
#define WS_E1 1606656     // 262144 ushorts (e1 tiles)
#define WS_E2 1737728     // 262144 ushorts (e2 tiles)
#define WS_LIST 1868800   // [32768] int refine rows
#define WS_CNT 1901568    // int refine count

#define DDIM 256
#define LOSS_OFF 8388608
#define IDX_OFF 8388609
#define Z2T_OFF 8388608   // ushort offset of z2t within out
#define REFINE_THR 1.5e-4f

typedef __attribute__((ext_vector_type(8))) short bf16x8;
typedef __attribute__((ext_vector_type(4))) float f32x4;
typedef __attribute__((ext_vector_type(8))) ushort u16x8;

__device__ __forceinline__ ushort bf16_rne(float x) {
  unsigned u = __float_as_uint(x);
  return (ushort)((u + 0x7FFFu + ((u >> 16) & 1u)) >> 16);
}
__device__ __forceinline__ float bf16f(ushort h) {
  return __uint_as_float(((unsigned)h) << 16);
}
__device__ __forceinline__ void gld16(void* l, const void* g) {
  __builtin_amdgcn_global_load_lds(
      (const __attribute__((address_space(1))) unsigned int*)g,
      (__attribute__((address_space(3))) unsigned int*)l, 16, 0, 0);
}

// ---------------- A1: e split+tile, B_k, zero counters ----------------------
// 8 threads per code (one per s-octant); B_k via fixed-tree shfl (deterministic).
__global__ __launch_bounds__(256) void k_eprep(const float* __restrict__ emb,
                                               float* __restrict__ ws,
                                               float* __restrict__ out) {
  const int g = blockIdx.x * 256 + threadIdx.x;   // 0..8191
  if (g == 0) { out[LOSS_OFF] = 0.0f; ((int*)ws)[WS_CNT] = 0; }
  const int k = g >> 3;                            // code 0..1023
  const int s = g & 7;                             // octant
  const int ct = k >> 7, n = k & 127;
  const float* er = emb + k * DDIM + s * 32;
  ushort* e1t = (ushort*)(ws + WS_E1);
  ushort* e2t = (ushort*)(ws + WS_E2);
  float bsum = 0.f;
#pragma unroll
  for (int kq = 0; kq < 4; ++kq) {
    const float4 v0 = *(const float4*)(er + kq * 8);
    const float4 v1 = *(const float4*)(er + kq * 8 + 4);
    const float v[8] = {v0.x, v0.y, v0.z, v0.w, v1.x, v1.y, v1.z, v1.w};
    u16x8 h, l;
#pragma unroll
    for (int j = 0; j < 8; ++j) {
      bsum = fmaf(v[j], v[j], bsum);
      h[j] = bf16_rne(v[j]);
      l[j] = bf16_rne(v[j] - bf16f(h[j]));
    }
    const int off = ((ct * 8 + s) * 4 + kq) * 1024 + n * 8;
    *(u16x8*)(e1t + off) = h;
    *(u16x8*)(e2t + off) = l;
  }
  bsum += __shfl_xor(bsum, 1);
  bsum += __shfl_xor(bsum, 2);
  bsum += __shfl_xor(bsum, 4);
  if (s == 0) ws[WS_B + k] = bsum;
}

// ---------------- A2: z transpose + split + tile + ||z_n||^2 ----------------
__global__ __launch_bounds__(256) void k_zprep(const float* __restrict__ z,
                                               float* __restrict__ out,
                                               float* __restrict__ ws) {
  __shared__ float lt[64][132];
  __shared__ float sq[128];
  const int tid = threadIdx.x;
  const int rt = blockIdx.x;
  const int b = rt >> 3;
  const int hw0 = (rt & 7) << 7;
  ushort* z1t = (ushort*)out;
  ushort* z2t = (ushort*)out + Z2T_OFF;
  const int m = tid & 127, half = tid >> 7;   // write roles
  const int lc = tid >> 2, lq = tid & 3;      // load roles
  float as[4] = {0.f, 0.f, 0.f, 0.f};
  for (int p = 0; p < 4; ++p) {
    const float* src = z + b * 262144 + ((p << 6) + lc) * 1024 + hw0 + (lq << 5);
#pragma unroll
    for (int i = 0; i < 8; ++i)
      *(float4*)&lt[lc][(lq << 5) + (i << 2)] = *(const float4*)(src + (i << 2));
    __syncthreads();
    const int s = (p << 1) + half;
#pragma unroll
    for (int kq = 0; kq < 4; ++kq) {
      u16x8 h, l;
#pragma unroll
      for (int j = 0; j < 8; ++j) {
        const float v = lt[(half << 5) + (kq << 3) + j][m];
        as[j & 3] = fmaf(v, v, as[j & 3]);
        h[j] = bf16_rne(v);
        l[j] = bf16_rne(v - bf16f(h[j]));
      }
      const int off = rt * 32768 + ((s << 2) + kq) * 1024 + (m << 3);
      *(u16x8*)(z1t + off) = h;
      *(u16x8*)(z2t + off) = l;
    }
    __syncthreads();
  }
  const float asum = (as[0] + as[1]) + (as[2] + as[3]);
  if (half) sq[m] = asum;
  __syncthreads();
  if (!half) ws[WS_A + rt * 128 + m] = asum + sq[m];
}

// ---------------- B: MFMA score GEMM — counted-vmcnt pipeline ---------------
// Block 128x128 (4 waves, 2x2, 64x64/wave), BK=32, LDS 64 KB dbuf, staging =
// global_load_lds (wave w owns array w: z1,z2,e1,e2). 2-deep prefetch:
// per step, vmcnt(8) keeps the newest stage's 8 loads in flight across the
// raw barriers (no __syncthreads -> no vmcnt(0) drain). setprio around MFMA.
__global__ __launch_bounds__(256, 2) void k_score(const float* __restrict__ out,
                                                  float* __restrict__ ws) {
  __shared__ __align__(16) ushort lds[2][16384];
  const int tid = threadIdx.x;
  const int id = blockIdx.x;
  const int rt = ((id >> 6) << 3) | (id & 7);   // 8 ct-blocks of one rt per XCD
  const int ct = (id >> 3) & 7;
  const int row0 = rt << 7;
  const int k0e = ct << 7;

  const ushort* z1t = (const ushort*)out;
  const ushort* z2t = (const ushort*)out + Z2T_OFF;
  const ushort* e1t = (const ushort*)(ws + WS_E1);
  const ushort* e2t = (const ushort*)(ws + WS_E2);

  const int w = tid >> 6, L = tid & 63;
  const int l15 = L & 15, kq = L >> 4;
  const int wr = w >> 1, wc = w & 1;

  const ushort* gbase = (w == 0) ? z1t + rt * 32768
                      : (w == 1) ? z2t + rt * 32768
                      : (w == 2) ? e1t + ct * 32768
                                 : e2t + ct * 32768;
  auto stage = [&](int s, int bf) {
    const ushort* g = gbase + (s << 12) + (L << 3);
#pragma unroll
    for (int i = 0; i < 8; ++i)
      gld16(&lds[bf][(w << 12) + (i << 9)], g + (i << 9));
  };

  f32x4 acc[4][4];
#pragma unroll
  for (int i = 0; i < 4; ++i)
#pragma unroll
    for (int j = 0; j < 4; ++j) acc[i][j] = (f32x4){0.f, 0.f, 0.f, 0.f};

  stage(0, 0);   // 8 vmem
  stage(1, 1);   // 8 vmem -> 16 outstanding

  for (int s = 0; s < 8; ++s) {
    const int cur = s & 1;
    // stage(s) fully landed (oldest 8 retired); stage(s+1) may stay in flight
    if (s < 7) asm volatile("s_waitcnt vmcnt(8)" ::: "memory");
    else       asm volatile("s_waitcnt vmcnt(0)" ::: "memory");
    __builtin_amdgcn_sched_barrier(0);
    __builtin_amdgcn_s_barrier();      // all waves' stage(s) landed
    __builtin_amdgcn_sched_barrier(0);

    bf16x8 a1[4], a2[4], b1[4], b2[4];
#pragma unroll
    for (int mi = 0; mi < 4; ++mi) {
      const int off = (kq << 10) + (((wr << 6) + (mi << 4) + l15) << 3);
      a1[mi] = *(const bf16x8*)&lds[cur][off];
      a2[mi] = *(const bf16x8*)&lds[cur][4096 + off];
    }
#pragma unroll
    for (int nj = 0; nj < 4; ++nj) {
      const int off = (kq << 10) + (((wc << 6) + (nj << 4) + l15) << 3);
      b1[nj] = *(const bf16x8*)&lds[cur][8192 + off];
      b2[nj] = *(const bf16x8*)&lds[cur][12288 + off];
    }
    asm volatile("s_waitcnt lgkmcnt(0)" ::: "memory");
    __builtin_amdgcn_sched_barrier(0);
    __builtin_amdgcn_s_barrier();      // all reads of buf[cur] done -> reusable
    __builtin_amdgcn_sched_barrier(0);
    if (s < 6) stage(s + 2, cur);      // DMA overlaps the MFMA cluster

    __builtin_amdgcn_s_setprio(1);
#pragma unroll
    for (int mi = 0; mi < 4; ++mi)
#pragma unroll
      for (int nj = 0; nj < 4; ++nj) {
        acc[mi][nj] = __builtin_amdgcn_mfma_f32_16x16x32_bf16(a2[mi], b1[nj], acc[mi][nj], 0, 0, 0);
        acc[mi][nj] = __builtin_amdgcn_mfma_f32_16x16x32_bf16(a1[mi], b2[nj], acc[mi][nj], 0, 0, 0);
        acc[mi][nj] = __builtin_amdgcn_mfma_f32_16x16x32_bf16(a1[mi], b1[nj], acc[mi][nj], 0, 0, 0);
      }
    __builtin_amdgcn_s_setprio(0);
  }

  // epilogue: quantized score + per-chunk (v1, i1, v2) — identical to rounds 6/7
  const int tc = (ct << 1) + wc;
#pragma unroll
  for (int mi = 0; mi < 4; ++mi) {
#pragma unroll
    for (int r = 0; r < 4; ++r) {
      const int ng = row0 + (wr << 6) + (mi << 4) + (kq << 2) + r;
      const float A = ws[WS_A + ng];
      float v1 = 3.0e38f, v2 = 3.0e38f;
      int i1 = 0;
#pragma unroll
      for (int nj = 0; nj < 4; ++nj) {
        const int kg = k0e + (wc << 6) + (nj << 4) + l15;
        const float B = ws[WS_B + kg];
        const float sc = fmaf(-2.0f, acc[mi][nj][r], A + B);
        if (sc < v1) { v2 = v1; v1 = sc; i1 = kg; }
        else if (sc < v2) v2 = sc;
      }
#pragma unroll
      for (int o = 1; o < 16; o <<= 1) {
        const float ov1 = __shfl_xor(v1, o);
        const float ov2 = __shfl_xor(v2, o);
        const int oi1 = __shfl_xor(i1, o);
        v2 = fminf(fminf(v2, ov2), fmaxf(v1, ov1));
        if (ov1 < v1 || (ov1 == v1 && oi1 < i1)) { v1 = ov1; i1 = oi1; }
      }
      if (l15 == 0) {
        const int base = (tc << 15) + ng;
        ws[WS_PV1 + base] = v1;
        ws[WS_PI1 + base] = (float)i1;
        ws[WS_PV2 + base] = v2;
      }
    }
  }
}

// ---------------- B2: merge 16 chunks; gate -> refine list; loss ------------
__global__ __launch_bounds__(256) void k_reduce(float* __restrict__ ws,
                                                float* __restrict__ out) {
  const int tid = threadIdx.x;
  const int row = blockIdx.x * 256 + tid;
  float v1 = 3.0e38f, v2 = 3.0e38f, i1 = 0.f;
#pragma unroll
  for (int tc = 0; tc < 16; ++tc) {
    const int base = (tc << 15) + row;
    const float a1 = ws[WS_PV1 + base];
    const float ai = ws[WS_PI1 + base];
    const float a2 = ws[WS_PV2 + base];
    if (a1 < v1) { v2 = fminf(v1, a2); v1 = a1; i1 = ai; }
    else v2 = fminf(v2, a1);
  }
  out[IDX_OFF + row] = i1;
  if (v2 - v1 < REFINE_THR) {
    const int slot = atomicAdd((int*)ws + WS_CNT, 1);
    ((int*)ws)[WS_LIST + slot] = row;
  }
  float s = v1;
#pragma unroll
  for (int o = 32; o; o >>= 1) s += __shfl_down(s, o);
  __shared__ float sm[4];
  if ((tid & 63) == 0) sm[tid >> 6] = s;
  __syncthreads();
  if (tid == 0)
    atomicAdd(out + LOSS_OFF,
              (sm[0] + sm[1] + sm[2] + sm[3]) * (1.25f / 8388608.0f));
}

// ---------------- B3: exact re-solve, candidate chunks only -----------------
__global__ __launch_bounds__(256) void k_refine(const float* __restrict__ z,
                                                const float* __restrict__ emb,
                                                const float* __restrict__ ws,
                                                float* __restrict__ out) {
  __shared__ float zs[4][256];
  const int tid = threadIdx.x;
  const int w = tid >> 6, L = tid & 63;
  const int wg = blockIdx.x * 4 + w;
  const int cnt = ((const int*)ws)[WS_CNT];
  for (int e = wg; e < cnt; e += 1024) {
    const int row = ((const int*)ws)[WS_LIST + e];
    const int b = row >> 10, hw = row & 1023;
#pragma unroll
    for (int q = 0; q < 4; ++q)
      zs[w][(q << 6) + L] = z[b * 262144 + (((q << 6) + L) << 10) + hw];
    asm volatile("s_waitcnt lgkmcnt(0)" ::: "memory");
    float v1c = (L < 16) ? ws[WS_PV1 + (L << 15) + row] : 3.0e38f;
    float v1 = v1c;
#pragma unroll
    for (int o = 1; o < 64; o <<= 1) v1 = fminf(v1, __shfl_xor(v1, o));
    const float A = ws[WS_A + row];
    float bv = 3.0e38f;
    int bk = 0;
    for (int tc = 0; tc < 16; ++tc) {
      const float bc = __shfl(v1c, tc);
      if (bc <= v1 + REFINE_THR) {
        const int k = ((tc >> 1) << 7) + ((tc & 1) << 6) + L;
        const float* er = emb + k * DDIM;
        float s = 0.f;
        for (int d = 0; d < DDIM; ++d) s = fmaf(zs[w][d], er[d], s);
        const float sc = fmaf(-2.0f, s, A + ws[WS_B + k]);
        if (sc < bv) { bv = sc; bk = k; }   // tc ascending => lowest k kept
      }
    }
#pragma unroll
    for (int o = 1; o < 64; o <<= 1) {
      const float ov = __shfl_xor(bv, o);
      const int ok = __shfl_xor(bk, o);
      if (ov < bv || (ov == bv && ok < bk)) { bv = ov; bk = ok; }
    }
    if (L == 0) out[IDX_OFF + row] = (float)bk;
  }
}

// ---------------- C: z_q gather (pure) ----------------
__global__ __launch_bounds__(256) void k_gather(const float* __restrict__ emb,
                                                float* __restrict__ out) {
  const int tid = threadIdx.x;
  const int e0 = (blockIdx.x * 256 + tid) * 16;
  const int b = e0 >> 18;
  const int c = (e0 >> 10) & 255;
  const int n0 = (b << 10) + (e0 & 1023);
#pragma unroll
  for (int g = 0; g < 4; ++g) {
    float q[4];
#pragma unroll
    for (int j = 0; j < 4; ++j) {
      const int id = (int)(out[IDX_OFF + n0 + g * 4 + j] + 0.5f);
      q[j] = emb[id * DDIM + c];
    }
    const float4 qv = {q[0], q[1], q[2], q[3]};
    *(float4*)(out + e0 + g * 4) = qv;
  }
}

extern "C" void kernel_launch(void* const* d_in, const int* in_sizes, int n_in,
                              void* d_out, int out_size, void* d_ws, size_t ws_size,
                              hipStream_t stream) {
  const float* z = (const float*)d_in[0];
  const float* emb = (const float*)d_in[1];
  float* out = (float*)d_out;
  float* ws = (float*)d_ws;

  k_eprep<<<32, 256, 0, stream>>>(emb, ws, out);
  k_zprep<<<256, 256, 0, stream>>>(z, out, ws);
  k_score<<<2048, 256, 0, stream>>>(out, ws);
  k_reduce<<<128, 256, 0, stream>>>(ws, out);
  k_refine<<<256, 256, 0, stream>>>(z, emb, ws, out);
  k_gather<<<2048, 256, 0, stream>>>(emb, out);
}